// Round 5
// baseline (790.028 us; speedup 1.0000x reference)
//
#include <hip/hip_runtime.h>

#define NN 100000
#define EE 1600000
#define FIN 128
#define HH 64
#define CC 40
#define NB 98  // ceil(NN/1024) scan blocks

// ---- CSR build -------------------------------------------------------------
// rp holds counts at rp[1+d] (rp[0]=0 from memset), scanned in place.

__global__ void k_count(const int* __restrict__ dst, int* __restrict__ rp) {
  int e = blockIdx.x * blockDim.x + threadIdx.x;
  if (e < EE) atomicAdd(&rp[1 + dst[e]], 1);
}

// per-block inclusive scan of rp[1..NN]; also dinv[i] = rsqrt(cnt+1)
__global__ void __launch_bounds__(1024)
k_scan_a(int* __restrict__ rp, float* __restrict__ dinv, int* __restrict__ bsum) {
  __shared__ int sm[1024];
  int i = blockIdx.x * 1024 + threadIdx.x;
  int c = (i < NN) ? rp[i + 1] : 0;
  if (i < NN) dinv[i] = rsqrtf((float)(c + 1));
  sm[threadIdx.x] = c;
  __syncthreads();
#pragma unroll
  for (int off = 1; off < 1024; off <<= 1) {
    int v = (threadIdx.x >= off) ? sm[threadIdx.x - off] : 0;
    __syncthreads();
    sm[threadIdx.x] += v;
    __syncthreads();
  }
  if (i < NN) rp[i + 1] = sm[threadIdx.x];
  if (threadIdx.x == 1023) bsum[blockIdx.x] = sm[1023];
}

// exclusive scan of the NB block sums (single block)
__global__ void __launch_bounds__(128)
k_scan_b(int* __restrict__ bsum) {
  __shared__ int sm[128];
  int v = (threadIdx.x < NB) ? bsum[threadIdx.x] : 0;
  sm[threadIdx.x] = v;
  __syncthreads();
#pragma unroll
  for (int off = 1; off < 128; off <<= 1) {
    int u = (threadIdx.x >= off) ? sm[threadIdx.x - off] : 0;
    __syncthreads();
    sm[threadIdx.x] += u;
    __syncthreads();
  }
  bsum[threadIdx.x] = sm[threadIdx.x] - v;  // exclusive
}

__global__ void k_scan_c(int* __restrict__ rp, const int* __restrict__ bsum) {
  int i = blockIdx.x * blockDim.x + threadIdx.x;
  if (i < NN) rp[i + 1] += bsum[i >> 10];
}

// col[pos] = src, pos = wp[dst]++
__global__ void k_fill(const int* __restrict__ ei, int* __restrict__ wp,
                       int* __restrict__ col) {
  int e = blockIdx.x * blockDim.x + threadIdx.x;
  if (e < EE) {
    int s = ei[e];
    int d = ei[EE + e];
    int pos = atomicAdd(&wp[d], 1);
    col[pos] = s;
  }
}

// ---- layer compute ---------------------------------------------------------

// hs[N,64] = dinv[row] * (x[N,128] @ W[128,64]). Lane owns output column; W
// column in 128 VGPRs; 4 rows per wave-iteration for 4x memory-level
// parallelism (one row's 32 broadcast loads can't cover L2 latency).
__global__ void __launch_bounds__(256, 1)
k_gemm1(const float* __restrict__ x, const float* __restrict__ W,
        const float* __restrict__ dinv, float* __restrict__ hs) {
  const int lane = threadIdx.x & 63;
  float w[FIN];
#pragma unroll
  for (int k = 0; k < FIN; ++k) w[k] = W[k * HH + lane];
  int wid = blockIdx.x * (blockDim.x >> 6) + (threadIdx.x >> 6);
  int nw  = gridDim.x * (blockDim.x >> 6);
  for (int base = wid * 4; base < NN; base += nw * 4) {  // NN % 4 == 0
    const float4* xr0 = reinterpret_cast<const float4*>(x + (size_t)(base + 0) * FIN);
    const float4* xr1 = reinterpret_cast<const float4*>(x + (size_t)(base + 1) * FIN);
    const float4* xr2 = reinterpret_cast<const float4*>(x + (size_t)(base + 2) * FIN);
    const float4* xr3 = reinterpret_cast<const float4*>(x + (size_t)(base + 3) * FIN);
    float a00 = 0.f, a01 = 0.f, a02 = 0.f, a03 = 0.f;
    float a10 = 0.f, a11 = 0.f, a12 = 0.f, a13 = 0.f;
    float a20 = 0.f, a21 = 0.f, a22 = 0.f, a23 = 0.f;
    float a30 = 0.f, a31 = 0.f, a32 = 0.f, a33 = 0.f;
#pragma unroll
    for (int k4 = 0; k4 < FIN / 4; ++k4) {
      float w0 = w[4 * k4 + 0], w1 = w[4 * k4 + 1];
      float w2 = w[4 * k4 + 2], w3 = w[4 * k4 + 3];
      float4 v0 = xr0[k4];
      a00 += v0.x * w0; a01 += v0.y * w1; a02 += v0.z * w2; a03 += v0.w * w3;
      float4 v1 = xr1[k4];
      a10 += v1.x * w0; a11 += v1.y * w1; a12 += v1.z * w2; a13 += v1.w * w3;
      float4 v2 = xr2[k4];
      a20 += v2.x * w0; a21 += v2.y * w1; a22 += v2.z * w2; a23 += v2.w * w3;
      float4 v3 = xr3[k4];
      a30 += v3.x * w0; a31 += v3.y * w1; a32 += v3.z * w2; a33 += v3.w * w3;
    }
    hs[(size_t)(base + 0) * HH + lane] = ((a00 + a01) + (a02 + a03)) * dinv[base + 0];
    hs[(size_t)(base + 1) * HH + lane] = ((a10 + a11) + (a12 + a13)) * dinv[base + 1];
    hs[(size_t)(base + 2) * HH + lane] = ((a20 + a21) + (a22 + a23)) * dinv[base + 2];
    hs[(size_t)(base + 3) * HH + lane] = ((a30 + a31) + (a32 + a33)) * dinv[base + 3];
  }
}

// wave per node: h1[d] = relu(dinv[d] * (hs[d] + sum_{s in N(d)} hs[s]) + b1)
__global__ void __launch_bounds__(256)
k_agg1(const int* __restrict__ rp, const int* __restrict__ col,
       const float* __restrict__ hs, const float* __restrict__ dinv,
       const float* __restrict__ b1, float* __restrict__ h1) {
  const int lane = threadIdx.x & 63;
  int d = blockIdx.x * 4 + (threadIdx.x >> 6);
  if (d >= NN) return;
  int e   = rp[d];
  int end = rp[d + 1];
  float acc = hs[(size_t)d * HH + lane];
  for (; e + 1 < end; e += 2) {
    int s0 = col[e], s1 = col[e + 1];
    acc += hs[(size_t)s0 * HH + lane];
    acc += hs[(size_t)s1 * HH + lane];
  }
  if (e < end) acc += hs[(size_t)col[e] * HH + lane];
  float v = acc * dinv[d] + b1[lane];
  h1[(size_t)d * HH + lane] = v > 0.f ? v : 0.f;
}

// hs2[N,40] = dinv[row] * (h1[N,64] @ W2[64,40]); 4 rows per wave-iteration
__global__ void __launch_bounds__(256, 1)
k_gemm2(const float* __restrict__ h1, const float* __restrict__ W,
        const float* __restrict__ dinv, float* __restrict__ hs2) {
  const int lane = threadIdx.x & 63;
  float w[HH];
  if (lane < CC) {
#pragma unroll
    for (int k = 0; k < HH; ++k) w[k] = W[k * CC + lane];
  } else {
#pragma unroll
    for (int k = 0; k < HH; ++k) w[k] = 0.f;
  }
  int wid = blockIdx.x * (blockDim.x >> 6) + (threadIdx.x >> 6);
  int nw  = gridDim.x * (blockDim.x >> 6);
  for (int base = wid * 4; base < NN; base += nw * 4) {  // NN % 4 == 0
    const float4* xr0 = reinterpret_cast<const float4*>(h1 + (size_t)(base + 0) * HH);
    const float4* xr1 = reinterpret_cast<const float4*>(h1 + (size_t)(base + 1) * HH);
    const float4* xr2 = reinterpret_cast<const float4*>(h1 + (size_t)(base + 2) * HH);
    const float4* xr3 = reinterpret_cast<const float4*>(h1 + (size_t)(base + 3) * HH);
    float a00 = 0.f, a01 = 0.f, a02 = 0.f, a03 = 0.f;
    float a10 = 0.f, a11 = 0.f, a12 = 0.f, a13 = 0.f;
    float a20 = 0.f, a21 = 0.f, a22 = 0.f, a23 = 0.f;
    float a30 = 0.f, a31 = 0.f, a32 = 0.f, a33 = 0.f;
#pragma unroll
    for (int k4 = 0; k4 < HH / 4; ++k4) {
      float w0 = w[4 * k4 + 0], w1 = w[4 * k4 + 1];
      float w2 = w[4 * k4 + 2], w3 = w[4 * k4 + 3];
      float4 v0 = xr0[k4];
      a00 += v0.x * w0; a01 += v0.y * w1; a02 += v0.z * w2; a03 += v0.w * w3;
      float4 v1 = xr1[k4];
      a10 += v1.x * w0; a11 += v1.y * w1; a12 += v1.z * w2; a13 += v1.w * w3;
      float4 v2 = xr2[k4];
      a20 += v2.x * w0; a21 += v2.y * w1; a22 += v2.z * w2; a23 += v2.w * w3;
      float4 v3 = xr3[k4];
      a30 += v3.x * w0; a31 += v3.y * w1; a32 += v3.z * w2; a33 += v3.w * w3;
    }
    if (lane < CC) {
      hs2[(size_t)(base + 0) * CC + lane] = ((a00 + a01) + (a02 + a03)) * dinv[base + 0];
      hs2[(size_t)(base + 1) * CC + lane] = ((a10 + a11) + (a12 + a13)) * dinv[base + 1];
      hs2[(size_t)(base + 2) * CC + lane] = ((a20 + a21) + (a22 + a23)) * dinv[base + 2];
      hs2[(size_t)(base + 3) * CC + lane] = ((a30 + a31) + (a32 + a33)) * dinv[base + 3];
    }
  }
}

// wave per node: v = dinv[d]*(hs2[d]+sum hs2[s]) + b2; out = log_softmax(v)
__global__ void __launch_bounds__(256)
k_agg2(const int* __restrict__ rp, const int* __restrict__ col,
       const float* __restrict__ hs2, const float* __restrict__ dinv,
       const float* __restrict__ b2, float* __restrict__ out) {
  const int lane = threadIdx.x & 63;
  int d = blockIdx.x * 4 + (threadIdx.x >> 6);
  if (d >= NN) return;
  const bool act = lane < CC;
  int e   = rp[d];
  int end = rp[d + 1];
  float acc = act ? hs2[(size_t)d * CC + lane] : 0.f;
  for (; e + 1 < end; e += 2) {
    int s0 = col[e], s1 = col[e + 1];
    if (act) {
      acc += hs2[(size_t)s0 * CC + lane];
      acc += hs2[(size_t)s1 * CC + lane];
    }
  }
  if (e < end && act) acc += hs2[(size_t)col[e] * CC + lane];
  float v = act ? acc * dinv[d] + b2[lane] : -__builtin_inff();
  float m = v;
#pragma unroll
  for (int off = 32; off > 0; off >>= 1) m = fmaxf(m, __shfl_xor(m, off));
  float ex = act ? expf(v - m) : 0.f;
  float s = ex;
#pragma unroll
  for (int off = 32; off > 0; off >>= 1) s += __shfl_xor(s, off);
  if (act) out[(size_t)d * CC + lane] = v - m - logf(s);
}

extern "C" void kernel_launch(void* const* d_in, const int* in_sizes, int n_in,
                              void* d_out, int out_size, void* d_ws, size_t ws_size,
                              hipStream_t stream) {
  const float* x  = (const float*)d_in[0];
  const int*   ei = (const int*)d_in[1];
  const float* W1 = (const float*)d_in[2];
  const float* b1 = (const float*)d_in[3];
  const float* W2 = (const float*)d_in[4];
  const float* b2 = (const float*)d_in[5];
  float* out = (float*)d_out;

  // workspace layout (all 4-byte elems)
  float* dinv = (float*)d_ws;                    // NN
  int*   rp   = (int*)(dinv + NN);               // NN+1
  int*   wp   = rp + NN + 1;                     // NN
  int*   bsum = wp + NN;                         // 128
  int*   col  = bsum + 128;                      // EE
  float* hsA  = (float*)(col + EE);              // NN*64 (hs, then hs2 as NN*40)
  float* h1   = hsA + (size_t)NN * HH;           // NN*64
  // total ~58.9 MB

  hipMemsetAsync(rp, 0, (NN + 1) * sizeof(int), stream);

  k_count<<<(EE + 255) / 256, 256, 0, stream>>>(ei + EE, rp);
  k_scan_a<<<NB, 1024, 0, stream>>>(rp, dinv, bsum);
  k_scan_b<<<1, 128, 0, stream>>>(bsum);
  k_scan_c<<<(NN + 255) / 256, 256, 0, stream>>>(rp, bsum);
  hipMemcpyAsync(wp, rp, NN * sizeof(int), hipMemcpyDeviceToDevice, stream);
  k_fill<<<(EE + 255) / 256, 256, 0, stream>>>(ei, wp, col);

  k_gemm1<<<1024, 256, 0, stream>>>(x, W1, dinv, hsA);
  k_agg1<<<(NN + 3) / 4, 256, 0, stream>>>(rp, col, hsA, dinv, b1, h1);
  k_gemm2<<<1024, 256, 0, stream>>>(h1, W2, dinv, hsA);
  k_agg2<<<(NN + 3) / 4, 256, 0, stream>>>(rp, col, hsA, dinv, b2, out);
}

// Round 6
// 716.817 us; speedup vs baseline: 1.1021x; 1.1021x over previous
//
#include <hip/hip_runtime.h>

#define NN 100000
#define EE 1600000
#define FIN 128
#define HH 64
#define CC 40
#define NB 98  // ceil(NN/1024) scan blocks

// ---- CSR build -------------------------------------------------------------
// rp holds counts at rp[1+d] (rp[0]=0 from memset), scanned in place.

__global__ void k_count(const int* __restrict__ dst, int* __restrict__ rp) {
  int e = blockIdx.x * blockDim.x + threadIdx.x;
  if (e < EE) atomicAdd(&rp[1 + dst[e]], 1);
}

// per-block inclusive scan of rp[1..NN]; also dinv[i] = rsqrt(cnt+1)
__global__ void __launch_bounds__(1024)
k_scan_a(int* __restrict__ rp, float* __restrict__ dinv, int* __restrict__ bsum) {
  __shared__ int sm[1024];
  int i = blockIdx.x * 1024 + threadIdx.x;
  int c = (i < NN) ? rp[i + 1] : 0;
  if (i < NN) dinv[i] = rsqrtf((float)(c + 1));
  sm[threadIdx.x] = c;
  __syncthreads();
#pragma unroll
  for (int off = 1; off < 1024; off <<= 1) {
    int v = (threadIdx.x >= off) ? sm[threadIdx.x - off] : 0;
    __syncthreads();
    sm[threadIdx.x] += v;
    __syncthreads();
  }
  if (i < NN) rp[i + 1] = sm[threadIdx.x];
  if (threadIdx.x == 1023) bsum[blockIdx.x] = sm[1023];
}

// exclusive scan of the NB block sums (single block)
__global__ void __launch_bounds__(128)
k_scan_b(int* __restrict__ bsum) {
  __shared__ int sm[128];
  int v = (threadIdx.x < NB) ? bsum[threadIdx.x] : 0;
  sm[threadIdx.x] = v;
  __syncthreads();
#pragma unroll
  for (int off = 1; off < 128; off <<= 1) {
    int u = (threadIdx.x >= off) ? sm[threadIdx.x - off] : 0;
    __syncthreads();
    sm[threadIdx.x] += u;
    __syncthreads();
  }
  bsum[threadIdx.x] = sm[threadIdx.x] - v;  // exclusive
}

__global__ void k_scan_c(int* __restrict__ rp, const int* __restrict__ bsum) {
  int i = blockIdx.x * blockDim.x + threadIdx.x;
  if (i < NN) rp[i + 1] += bsum[i >> 10];
}

// col[pos] = src, pos = wp[dst]++
__global__ void k_fill(const int* __restrict__ ei, int* __restrict__ wp,
                       int* __restrict__ col) {
  int e = blockIdx.x * blockDim.x + threadIdx.x;
  if (e < EE) {
    int s = ei[e];
    int d = ei[EE + e];
    int pos = atomicAdd(&wp[d], 1);
    col[pos] = s;
  }
}

// ---- layer compute ---------------------------------------------------------

// hs[N,64] = dinv[row] * (x[N,128] @ W[128,64]).
// W transposed into LDS (stride 132 floats -> 16B-aligned, bank-spread): lane
// owns column, reads 4 w via one ds_read_b128 per 16 FMAs. 4 rows/wave-iter
// for MLP. Register pressure stays ~70 VGPR regardless of compiler mood.
__global__ void __launch_bounds__(256)
k_gemm1(const float* __restrict__ x, const float* __restrict__ W,
        const float* __restrict__ dinv, float* __restrict__ hs) {
  __shared__ float Wt[64 * 132];
  for (int i = threadIdx.x; i < FIN * HH; i += 256) {
    int k = i >> 6;   // W row-major [128][64]: i = k*64 + c
    int c = i & 63;
    Wt[c * 132 + k] = W[i];
  }
  __syncthreads();
  const int lane = threadIdx.x & 63;
  const float* wl = &Wt[lane * 132];
  int wid = blockIdx.x * (blockDim.x >> 6) + (threadIdx.x >> 6);
  int nw  = gridDim.x * (blockDim.x >> 6);
  for (int base = wid * 4; base < NN; base += nw * 4) {  // NN % 4 == 0
    const float4* xr0 = reinterpret_cast<const float4*>(x + (size_t)(base + 0) * FIN);
    const float4* xr1 = reinterpret_cast<const float4*>(x + (size_t)(base + 1) * FIN);
    const float4* xr2 = reinterpret_cast<const float4*>(x + (size_t)(base + 2) * FIN);
    const float4* xr3 = reinterpret_cast<const float4*>(x + (size_t)(base + 3) * FIN);
    float a0 = 0.f, a1 = 0.f, a2 = 0.f, a3 = 0.f;
#pragma unroll
    for (int k4 = 0; k4 < FIN / 4; ++k4) {
      float4 wv = *reinterpret_cast<const float4*>(wl + 4 * k4);
      float4 v0 = xr0[k4];
      a0 += v0.x * wv.x; a0 += v0.y * wv.y; a0 += v0.z * wv.z; a0 += v0.w * wv.w;
      float4 v1 = xr1[k4];
      a1 += v1.x * wv.x; a1 += v1.y * wv.y; a1 += v1.z * wv.z; a1 += v1.w * wv.w;
      float4 v2 = xr2[k4];
      a2 += v2.x * wv.x; a2 += v2.y * wv.y; a2 += v2.z * wv.z; a2 += v2.w * wv.w;
      float4 v3 = xr3[k4];
      a3 += v3.x * wv.x; a3 += v3.y * wv.y; a3 += v3.z * wv.z; a3 += v3.w * wv.w;
    }
    hs[(size_t)(base + 0) * HH + lane] = a0 * dinv[base + 0];
    hs[(size_t)(base + 1) * HH + lane] = a1 * dinv[base + 1];
    hs[(size_t)(base + 2) * HH + lane] = a2 * dinv[base + 2];
    hs[(size_t)(base + 3) * HH + lane] = a3 * dinv[base + 3];
  }
}

// wave per node: h1[d] = relu(dinv[d] * (hs[d] + sum_{s in N(d)} hs[s]) + b1)
__global__ void __launch_bounds__(256)
k_agg1(const int* __restrict__ rp, const int* __restrict__ col,
       const float* __restrict__ hs, const float* __restrict__ dinv,
       const float* __restrict__ b1, float* __restrict__ h1) {
  const int lane = threadIdx.x & 63;
  int d = blockIdx.x * 4 + (threadIdx.x >> 6);
  if (d >= NN) return;
  int e   = rp[d];
  int end = rp[d + 1];
  float acc = hs[(size_t)d * HH + lane];
  for (; e + 1 < end; e += 2) {
    int s0 = col[e], s1 = col[e + 1];
    acc += hs[(size_t)s0 * HH + lane];
    acc += hs[(size_t)s1 * HH + lane];
  }
  if (e < end) acc += hs[(size_t)col[e] * HH + lane];
  float v = acc * dinv[d] + b1[lane];
  h1[(size_t)d * HH + lane] = v > 0.f ? v : 0.f;
}

// hs2[N,40] = dinv[row] * (h1[N,64] @ W2[64,40]); same LDS-W structure,
// idle lanes (>=40) compute on zeros and don't store.
__global__ void __launch_bounds__(256)
k_gemm2(const float* __restrict__ h1, const float* __restrict__ W,
        const float* __restrict__ dinv, float* __restrict__ hs2) {
  __shared__ float Wt[64 * 68];
  for (int i = threadIdx.x; i < 64 * 68; i += 256) Wt[i] = 0.f;
  __syncthreads();
  for (int i = threadIdx.x; i < HH * CC; i += 256) {
    int k = i / CC;   // W2 row-major [64][40]: i = k*40 + c
    int c = i - k * CC;
    Wt[c * 68 + k] = W[i];
  }
  __syncthreads();
  const int lane = threadIdx.x & 63;
  const float* wl = &Wt[lane * 68];
  int wid = blockIdx.x * (blockDim.x >> 6) + (threadIdx.x >> 6);
  int nw  = gridDim.x * (blockDim.x >> 6);
  for (int base = wid * 4; base < NN; base += nw * 4) {  // NN % 4 == 0
    const float4* xr0 = reinterpret_cast<const float4*>(h1 + (size_t)(base + 0) * HH);
    const float4* xr1 = reinterpret_cast<const float4*>(h1 + (size_t)(base + 1) * HH);
    const float4* xr2 = reinterpret_cast<const float4*>(h1 + (size_t)(base + 2) * HH);
    const float4* xr3 = reinterpret_cast<const float4*>(h1 + (size_t)(base + 3) * HH);
    float a0 = 0.f, a1 = 0.f, a2 = 0.f, a3 = 0.f;
#pragma unroll
    for (int k4 = 0; k4 < HH / 4; ++k4) {
      float4 wv = *reinterpret_cast<const float4*>(wl + 4 * k4);
      float4 v0 = xr0[k4];
      a0 += v0.x * wv.x; a0 += v0.y * wv.y; a0 += v0.z * wv.z; a0 += v0.w * wv.w;
      float4 v1 = xr1[k4];
      a1 += v1.x * wv.x; a1 += v1.y * wv.y; a1 += v1.z * wv.z; a1 += v1.w * wv.w;
      float4 v2 = xr2[k4];
      a2 += v2.x * wv.x; a2 += v2.y * wv.y; a2 += v2.z * wv.z; a2 += v2.w * wv.w;
      float4 v3 = xr3[k4];
      a3 += v3.x * wv.x; a3 += v3.y * wv.y; a3 += v3.z * wv.z; a3 += v3.w * wv.w;
    }
    if (lane < CC) {
      hs2[(size_t)(base + 0) * CC + lane] = a0 * dinv[base + 0];
      hs2[(size_t)(base + 1) * CC + lane] = a1 * dinv[base + 1];
      hs2[(size_t)(base + 2) * CC + lane] = a2 * dinv[base + 2];
      hs2[(size_t)(base + 3) * CC + lane] = a3 * dinv[base + 3];
    }
  }
}

// wave per node: v = dinv[d]*(hs2[d]+sum hs2[s]) + b2; out = log_softmax(v)
__global__ void __launch_bounds__(256)
k_agg2(const int* __restrict__ rp, const int* __restrict__ col,
       const float* __restrict__ hs2, const float* __restrict__ dinv,
       const float* __restrict__ b2, float* __restrict__ out) {
  const int lane = threadIdx.x & 63;
  int d = blockIdx.x * 4 + (threadIdx.x >> 6);
  if (d >= NN) return;
  const bool act = lane < CC;
  int e   = rp[d];
  int end = rp[d + 1];
  float acc = act ? hs2[(size_t)d * CC + lane] : 0.f;
  for (; e + 1 < end; e += 2) {
    int s0 = col[e], s1 = col[e + 1];
    if (act) {
      acc += hs2[(size_t)s0 * CC + lane];
      acc += hs2[(size_t)s1 * CC + lane];
    }
  }
  if (e < end && act) acc += hs2[(size_t)col[e] * CC + lane];
  float v = act ? acc * dinv[d] + b2[lane] : -__builtin_inff();
  float m = v;
#pragma unroll
  for (int off = 32; off > 0; off >>= 1) m = fmaxf(m, __shfl_xor(m, off));
  float ex = act ? expf(v - m) : 0.f;
  float s = ex;
#pragma unroll
  for (int off = 32; off > 0; off >>= 1) s += __shfl_xor(s, off);
  if (act) out[(size_t)d * CC + lane] = v - m - logf(s);
}

extern "C" void kernel_launch(void* const* d_in, const int* in_sizes, int n_in,
                              void* d_out, int out_size, void* d_ws, size_t ws_size,
                              hipStream_t stream) {
  const float* x  = (const float*)d_in[0];
  const int*   ei = (const int*)d_in[1];
  const float* W1 = (const float*)d_in[2];
  const float* b1 = (const float*)d_in[3];
  const float* W2 = (const float*)d_in[4];
  const float* b2 = (const float*)d_in[5];
  float* out = (float*)d_out;

  // workspace layout (all 4-byte elems)
  float* dinv = (float*)d_ws;                    // NN
  int*   rp   = (int*)(dinv + NN);               // NN+1
  int*   wp   = rp + NN + 1;                     // NN
  int*   bsum = wp + NN;                         // 128
  int*   col  = bsum + 128;                      // EE
  float* hsA  = (float*)(col + EE);              // NN*64 (hs, then hs2 as NN*40)
  float* h1   = hsA + (size_t)NN * HH;           // NN*64
  // total ~58.9 MB

  hipMemsetAsync(rp, 0, (NN + 1) * sizeof(int), stream);

  k_count<<<(EE + 255) / 256, 256, 0, stream>>>(ei + EE, rp);
  k_scan_a<<<NB, 1024, 0, stream>>>(rp, dinv, bsum);
  k_scan_b<<<1, 128, 0, stream>>>(bsum);
  k_scan_c<<<(NN + 255) / 256, 256, 0, stream>>>(rp, bsum);
  hipMemcpyAsync(wp, rp, NN * sizeof(int), hipMemcpyDeviceToDevice, stream);
  k_fill<<<(EE + 255) / 256, 256, 0, stream>>>(ei, wp, col);

  k_gemm1<<<1024, 256, 0, stream>>>(x, W1, dinv, hsA);
  k_agg1<<<(NN + 3) / 4, 256, 0, stream>>>(rp, col, hsA, dinv, b1, h1);
  k_gemm2<<<1024, 256, 0, stream>>>(h1, W2, dinv, hsA);
  k_agg2<<<(NN + 3) / 4, 256, 0, stream>>>(rp, col, hsA, dinv, b2, out);
}

// Round 11
// 587.731 us; speedup vs baseline: 1.3442x; 1.2196x over previous
//
#include <hip/hip_runtime.h>

#define NN 100000
#define EE 1600000
#define FIN 128
#define HH 64
#define CC 40
#define NB 98   // ceil(NN/1024) scan blocks
#define TR 64   // rows per tile

// ---- CSR build -------------------------------------------------------------

__global__ void k_count(const int* __restrict__ dst, int* __restrict__ rp) {
  int e = blockIdx.x * blockDim.x + threadIdx.x;
  if (e < EE) atomicAdd(&rp[1 + dst[e]], 1);
}

__global__ void __launch_bounds__(1024)
k_scan_a(int* __restrict__ rp, float* __restrict__ dinv, int* __restrict__ bsum) {
  __shared__ int sm[1024];
  int i = blockIdx.x * 1024 + threadIdx.x;
  int c = (i < NN) ? rp[i + 1] : 0;
  if (i < NN) dinv[i] = rsqrtf((float)(c + 1));
  sm[threadIdx.x] = c;
  __syncthreads();
#pragma unroll
  for (int off = 1; off < 1024; off <<= 1) {
    int v = (threadIdx.x >= off) ? sm[threadIdx.x - off] : 0;
    __syncthreads();
    sm[threadIdx.x] += v;
    __syncthreads();
  }
  if (i < NN) rp[i + 1] = sm[threadIdx.x];
  if (threadIdx.x == 1023) bsum[blockIdx.x] = sm[1023];
}

__global__ void __launch_bounds__(128)
k_scan_b(int* __restrict__ bsum) {
  __shared__ int sm[128];
  int v = (threadIdx.x < NB) ? bsum[threadIdx.x] : 0;
  sm[threadIdx.x] = v;
  __syncthreads();
#pragma unroll
  for (int off = 1; off < 128; off <<= 1) {
    int u = (threadIdx.x >= off) ? sm[threadIdx.x - off] : 0;
    __syncthreads();
    sm[threadIdx.x] += u;
    __syncthreads();
  }
  bsum[threadIdx.x] = sm[threadIdx.x] - v;  // exclusive
}

__global__ void k_scan_c(int* __restrict__ rp, const int* __restrict__ bsum) {
  int i = blockIdx.x * blockDim.x + threadIdx.x;
  if (i < NN) rp[i + 1] += bsum[i >> 10];
}

__global__ void k_fill(const int* __restrict__ ei, int* __restrict__ wp,
                       int* __restrict__ col) {
  int e = blockIdx.x * blockDim.x + threadIdx.x;
  if (e < EE) {
    int s = ei[e];
    int d = ei[EE + e];
    int pos = atomicAdd(&wp[d], 1);
    col[pos] = s;
  }
}

// ---- layer compute ---------------------------------------------------------

// hs[N,64] = dinv[row] * (x @ W1).  Tile GEMM:
//  - 64-row x tile staged to LDS via per-lane coalesced float4 (MLP at HBM)
//  - wave computes 16 rows; x read as uniform-addr b128 broadcast (no banks)
//  - W chunked 32 k at a time into 32 VGPRs via coalesced L2-hot loads
__global__ void __launch_bounds__(256)
k_gemm1(const float* __restrict__ x, const float* __restrict__ W,
        const float* __restrict__ dinv, float* __restrict__ hs) {
  __shared__ float xs[TR * FIN];  // 32 KB
  const int tid  = threadIdx.x;
  const int lane = tid & 63;
  const int wq   = tid >> 6;
  int base = blockIdx.x * TR;
  int rows = NN - base; if (rows > TR) rows = TR;

  {  // stage tile (coalesced)
    const float4* xg = reinterpret_cast<const float4*>(x + (size_t)base * FIN);
    float4* xsv = reinterpret_cast<float4*>(xs);
    int n4 = rows * (FIN / 4);
    for (int i = tid; i < n4; i += 256) xsv[i] = xg[i];
  }
  __syncthreads();

  const int r0 = wq * 16;
  float acc[16];
#pragma unroll
  for (int r = 0; r < 16; ++r) acc[r] = 0.f;

  for (int kc = 0; kc < 4; ++kc) {  // k chunks of 32
    float wreg[32];
#pragma unroll
    for (int j = 0; j < 32; ++j) wreg[j] = W[(kc * 32 + j) * HH + lane];
#pragma unroll
    for (int r = 0; r < 16; ++r) {
      const float* xrow = &xs[(r0 + r) * FIN + kc * 32];
#pragma unroll
      for (int k4 = 0; k4 < 8; ++k4) {
        float4 xv = *reinterpret_cast<const float4*>(xrow + 4 * k4);
        acc[r] += xv.x * wreg[4 * k4 + 0];
        acc[r] += xv.y * wreg[4 * k4 + 1];
        acc[r] += xv.z * wreg[4 * k4 + 2];
        acc[r] += xv.w * wreg[4 * k4 + 3];
      }
    }
  }
#pragma unroll
  for (int r = 0; r < 16; ++r) {
    int row = base + r0 + r;
    if (r0 + r < rows) hs[(size_t)row * HH + lane] = acc[r] * dinv[row];
  }
}

// wave per node: h1[d] = relu(dinv[d] * (hs[d] + sum_{s in N(d)} hs[s]) + b1)
__global__ void __launch_bounds__(256)
k_agg1(const int* __restrict__ rp, const int* __restrict__ col,
       const float* __restrict__ hs, const float* __restrict__ dinv,
       const float* __restrict__ b1, float* __restrict__ h1) {
  const int lane = threadIdx.x & 63;
  int d = blockIdx.x * 4 + (threadIdx.x >> 6);
  if (d >= NN) return;
  int e   = rp[d];
  int end = rp[d + 1];
  float acc = hs[(size_t)d * HH + lane];
  for (; e + 1 < end; e += 2) {
    int s0 = col[e], s1 = col[e + 1];
    acc += hs[(size_t)s0 * HH + lane];
    acc += hs[(size_t)s1 * HH + lane];
  }
  if (e < end) acc += hs[(size_t)col[e] * HH + lane];
  float v = acc * dinv[d] + b1[lane];
  h1[(size_t)d * HH + lane] = v > 0.f ? v : 0.f;
}

// hs2[N,40] = dinv[row] * (h1 @ W2).  Same tile structure, K=64.
__global__ void __launch_bounds__(256)
k_gemm2(const float* __restrict__ h1, const float* __restrict__ W,
        const float* __restrict__ dinv, float* __restrict__ hs2) {
  __shared__ float xs[TR * HH];  // 16 KB
  const int tid  = threadIdx.x;
  const int lane = tid & 63;
  const int wq   = tid >> 6;
  const int cl   = lane < CC ? lane : CC - 1;  // clamped W column
  int base = blockIdx.x * TR;
  int rows = NN - base; if (rows > TR) rows = TR;

  {
    const float4* xg = reinterpret_cast<const float4*>(h1 + (size_t)base * HH);
    float4* xsv = reinterpret_cast<float4*>(xs);
    int n4 = rows * (HH / 4);
    for (int i = tid; i < n4; i += 256) xsv[i] = xg[i];
  }
  __syncthreads();

  const int r0 = wq * 16;
  float acc[16];
#pragma unroll
  for (int r = 0; r < 16; ++r) acc[r] = 0.f;

  for (int kc = 0; kc < 2; ++kc) {
    float wreg[32];
#pragma unroll
    for (int j = 0; j < 32; ++j) wreg[j] = W[(kc * 32 + j) * CC + cl];
#pragma unroll
    for (int r = 0; r < 16; ++r) {
      const float* xrow = &xs[(r0 + r) * HH + kc * 32];
#pragma unroll
      for (int k4 = 0; k4 < 8; ++k4) {
        float4 xv = *reinterpret_cast<const float4*>(xrow + 4 * k4);
        acc[r] += xv.x * wreg[4 * k4 + 0];
        acc[r] += xv.y * wreg[4 * k4 + 1];
        acc[r] += xv.z * wreg[4 * k4 + 2];
        acc[r] += xv.w * wreg[4 * k4 + 3];
      }
    }
  }
#pragma unroll
  for (int r = 0; r < 16; ++r) {
    int row = base + r0 + r;
    if (r0 + r < rows && lane < CC)
      hs2[(size_t)row * CC + lane] = acc[r] * dinv[row];
  }
}

// wave per node: v = dinv[d]*(hs2[d]+sum hs2[s]) + b2; out = log_softmax(v)
__global__ void __launch_bounds__(256)
k_agg2(const int* __restrict__ rp, const int* __restrict__ col,
       const float* __restrict__ hs2, const float* __restrict__ dinv,
       const float* __restrict__ b2, float* __restrict__ out) {
  const int lane = threadIdx.x & 63;
  int d = blockIdx.x * 4 + (threadIdx.x >> 6);
  if (d >= NN) return;
  const bool act = lane < CC;
  int e   = rp[d];
  int end = rp[d + 1];
  float acc = act ? hs2[(size_t)d * CC + lane] : 0.f;
  for (; e + 1 < end; e += 2) {
    int s0 = col[e], s1 = col[e + 1];
    if (act) {
      acc += hs2[(size_t)s0 * CC + lane];
      acc += hs2[(size_t)s1 * CC + lane];
    }
  }
  if (e < end && act) acc += hs2[(size_t)col[e] * CC + lane];
  float v = act ? acc * dinv[d] + b2[lane] : -__builtin_inff();
  float m = v;
#pragma unroll
  for (int off = 32; off > 0; off >>= 1) m = fmaxf(m, __shfl_xor(m, off));
  float ex = act ? expf(v - m) : 0.f;
  float s = ex;
#pragma unroll
  for (int off = 32; off > 0; off >>= 1) s += __shfl_xor(s, off);
  if (act) out[(size_t)d * CC + lane] = v - m - logf(s);
}

extern "C" void kernel_launch(void* const* d_in, const int* in_sizes, int n_in,
                              void* d_out, int out_size, void* d_ws, size_t ws_size,
                              hipStream_t stream) {
  const float* x  = (const float*)d_in[0];
  const int*   ei = (const int*)d_in[1];
  const float* W1 = (const float*)d_in[2];
  const float* b1 = (const float*)d_in[3];
  const float* W2 = (const float*)d_in[4];
  const float* b2 = (const float*)d_in[5];
  float* out = (float*)d_out;

  // workspace layout (all 4-byte elems)
  float* dinv = (float*)d_ws;                    // NN
  int*   rp   = (int*)(dinv + NN);               // NN+1
  int*   wp   = rp + NN + 1;                     // NN
  int*   bsum = wp + NN;                         // 128
  int*   col  = bsum + 128;                      // EE
  float* hsA  = (float*)(col + EE);              // NN*64 (hs, then hs2 as NN*40)
  float* h1   = hsA + (size_t)NN * HH;           // NN*64
  // total ~58.9 MB

  hipMemsetAsync(rp, 0, (NN + 1) * sizeof(int), stream);

  k_count<<<(EE + 255) / 256, 256, 0, stream>>>(ei + EE, rp);
  k_scan_a<<<NB, 1024, 0, stream>>>(rp, dinv, bsum);
  k_scan_b<<<1, 128, 0, stream>>>(bsum);
  k_scan_c<<<(NN + 255) / 256, 256, 0, stream>>>(rp, bsum);
  hipMemcpyAsync(wp, rp, NN * sizeof(int), hipMemcpyDeviceToDevice, stream);
  k_fill<<<(EE + 255) / 256, 256, 0, stream>>>(ei, wp, col);

  int tiles = (NN + TR - 1) / TR;  // 1563
  k_gemm1<<<tiles, 256, 0, stream>>>(x, W1, dinv, hsA);
  k_agg1<<<(NN + 3) / 4, 256, 0, stream>>>(rp, col, hsA, dinv, b1, h1);
  k_gemm2<<<tiles, 256, 0, stream>>>(h1, W2, dinv, hsA);
  k_agg2<<<(NN + 3) / 4, 256, 0, stream>>>(rp, col, hsA, dinv, b2, out);
}